// Round 18
// baseline (141.832 us; speedup 1.0000x reference)
//
#include <hip/hip_runtime.h>
#include <math.h>

#define N_NODES 100000
#define N_EDGES 1600000
#define D 64
#define DOUT 40
#define NBUCK ((N_NODES + 255) / 256)    // 391 buckets of 256 dst-nodes
#define CHUNK 4096                       // edges per prep block (write locality!)
#define NCHUNK ((N_EDGES + CHUNK - 1) / CHUNK)  // 391 chunks
#define PTHREADS 512                     // prep block width (8 waves)
#define BCAP 4864                        // bucket region capacity (mean 4096 + 12 sigma)

typedef __attribute__((ext_vector_type(8))) short bf16x8v;   // 8 bf16 (4 VGPRs)
typedef __attribute__((ext_vector_type(4))) float f32x4v;    // MFMA accumulator
typedef __attribute__((ext_vector_type(2))) float f32x2v;    // fp8 cvt result

__device__ inline float bf2f(unsigned u) {
  union { unsigned i; float f; } v;
  v.i = u << 16;
  return v.f;
}
__device__ inline unsigned f2bf(float f) {
  union { float f; unsigned i; } v;
  v.f = f;
  unsigned r = v.i + 0x7fffu + ((v.i >> 16) & 1u);   // RNE
  return r >> 16;
}
__device__ inline unsigned char f2fp8(float f) {     // OCP e4m3 via HW cvt
  int v = __builtin_amdgcn_cvt_pk_fp8_f32(f, f, 0, false);
  return (unsigned char)(v & 0xFF);
}
// decode+accumulate 8 fp8 feats (uint2 = 8B) into 4x float2
__device__ inline void addrow8(float2* A, uint2 r) {
  f32x2v p0 = __builtin_amdgcn_cvt_pk_f32_fp8(r.x, false);
  f32x2v p1 = __builtin_amdgcn_cvt_pk_f32_fp8(r.x, true);
  f32x2v p2 = __builtin_amdgcn_cvt_pk_f32_fp8(r.y, false);
  f32x2v p3 = __builtin_amdgcn_cvt_pk_f32_fp8(r.y, true);
  A[0].x += p0[0]; A[0].y += p0[1];
  A[1].x += p1[0]; A[1].y += p1[1];
  A[2].x += p2[0]; A[2].y += p2[1];
  A[3].x += p3[0]; A[3].y += p3[1];
}

// ---------------------------------------------------------------------------
// prep_kernel: cvt(x->bf16 AND fp8) + weight prep + single-pass bucket scatter.
// ---------------------------------------------------------------------------
__global__ __launch_bounds__(PTHREADS) void prep_kernel(
    const float* __restrict__ x, unsigned short* __restrict__ xbf,
    unsigned char* __restrict__ xf8,
    const float* __restrict__ W1l, const float* __restrict__ W1r,
    const float* __restrict__ W2l, const float* __restrict__ W2r,
    const float* __restrict__ b2, unsigned short* __restrict__ Wcat1,
    unsigned short* __restrict__ Wcat2, float* __restrict__ b2p,
    const int* __restrict__ src, const int* __restrict__ dst,
    int* __restrict__ bcnt, unsigned* __restrict__ binned) {
  __shared__ unsigned ent[CHUNK];
  __shared__ unsigned short sbk[CHUNK];
  __shared__ int cnt[512], scn[512], pos[512], base[512];
  int t = threadIdx.x;
  int blk = blockIdx.x;
  int gtid = blk * PTHREADS + t;
  int nth = NCHUNK * PTHREADS;

  const int n8 = N_NODES * D / 8;
  for (int i = gtid; i < n8; i += nth) {
    const float4* p = reinterpret_cast<const float4*>(x) + (size_t)i * 2;
    float4 a = p[0], b = p[1];
    uint4 o;
    o.x = f2bf(a.x) | (f2bf(a.y) << 16);
    o.y = f2bf(a.z) | (f2bf(a.w) << 16);
    o.z = f2bf(b.x) | (f2bf(b.y) << 16);
    o.w = f2bf(b.z) | (f2bf(b.w) << 16);
    reinterpret_cast<uint4*>(xbf)[i] = o;
    int u0 = 0, u1 = 0;
    u0 = __builtin_amdgcn_cvt_pk_fp8_f32(a.x, a.y, u0, false);
    u0 = __builtin_amdgcn_cvt_pk_fp8_f32(a.z, a.w, u0, true);
    u1 = __builtin_amdgcn_cvt_pk_fp8_f32(b.x, b.y, u1, false);
    u1 = __builtin_amdgcn_cvt_pk_fp8_f32(b.z, b.w, u1, true);
    uint2 o8; o8.x = (unsigned)u0; o8.y = (unsigned)u1;
    *reinterpret_cast<uint2*>(xf8 + (size_t)i * 8) = o8;
  }
  const int NW = 64 * 128 + 48 * 128 + 48;
  for (int i = gtid; i < NW; i += nth) {
    if (i < 64 * 128) {
      int o = i >> 7, k = i & 127;
      float v = (k < 64) ? W1l[o * 64 + k] : W1r[o * 64 + (k - 64)];
      Wcat1[i] = (unsigned short)f2bf(v);
    } else if (i < 64 * 128 + 48 * 128) {
      int j = i - 64 * 128;
      int o = j >> 7, k = j & 127;
      float v = (o < DOUT) ? ((k < 64) ? W2l[o * 64 + k] : W2r[o * 64 + (k - 64)]) : 0.0f;
      Wcat2[j] = (unsigned short)f2bf(v);
    } else {
      int j = i - 64 * 128 - 48 * 128;
      b2p[j] = (j < DOUT) ? b2[j] : 0.0f;
    }
  }
  cnt[t] = 0;
  __syncthreads();
  int cbase = blk * CHUNK;
  int cc = min(CHUNK, N_EDGES - cbase);
  unsigned my_e[8];
  int my_b[8];
  int nmine = 0;
#pragma unroll
  for (int i = 0; i < 8; ++i) {
    int li = t + i * PTHREADS;
    if (li < cc) {
      int s = src[cbase + li];
      int d = dst[cbase + li];
      int b = d >> 8;
      my_e[nmine] = ((unsigned)(d & 255) << 24) | (unsigned)s;
      my_b[nmine] = b;
      nmine++;
      atomicAdd(&cnt[b], 1);
    }
  }
  __syncthreads();
  scn[t] = cnt[t];
  __syncthreads();
  for (int off = 1; off < 512; off <<= 1) {
    int v = (t >= off) ? scn[t - off] : 0;
    __syncthreads();
    scn[t] += v;
    __syncthreads();
  }
  pos[t] = scn[t] - cnt[t];
  __syncthreads();
  for (int i = 0; i < nmine; ++i) {
    int slot = atomicAdd(&pos[my_b[i]], 1);
    ent[slot] = my_e[i];
    sbk[slot] = (unsigned short)my_b[i];
  }
  __syncthreads();
  for (int b = t; b < NBUCK; b += PTHREADS)
    if (cnt[b] > 0) base[b] = atomicAdd(&bcnt[b], cnt[b]);
  __syncthreads();
  for (int i = t; i < cc; i += PTHREADS) {
    int b = sbk[i];
    int excl = scn[b] - cnt[b];
    binned[(size_t)b * BCAP + base[b] + (i - excl)] = ent[i];
  }
}

// ---------------------------------------------------------------------------
// fine_kernel: per-bucket counting-sort -> csr (fixed regions) + rs/re.
// ---------------------------------------------------------------------------
__global__ __launch_bounds__(512) void fine_kernel(
    const unsigned* __restrict__ binned, const int* __restrict__ bcnt,
    int* __restrict__ rs, int* __restrict__ re_, int* __restrict__ csr, int N) {
  __shared__ unsigned ent[BCAP];
  __shared__ int c[256], p[256], pos[256];
  int b = blockIdx.x;
  int t = threadIdx.x;
  int cc = bcnt[b];
  int s0 = b * BCAP;
  if (t < 256) c[t] = 0;
  __syncthreads();
  for (int i = t; i < cc; i += 512) {
    unsigned u = binned[s0 + i];
    ent[i] = u;
    atomicAdd(&c[u >> 24], 1);
  }
  __syncthreads();
  if (t < 256) p[t] = c[t];
  __syncthreads();
  for (int off = 1; off < 256; off <<= 1) {
    int v = 0;
    if (t < 256 && t >= off) v = p[t - off];
    __syncthreads();
    if (t < 256) p[t] += v;
    __syncthreads();
  }
  if (t < 256) {
    int excl = p[t] - c[t];
    int node = b * 256 + t;
    if (node < N) {
      rs[node] = s0 + excl;
      re_[node] = s0 + excl + c[t];
    }
    pos[t] = excl;
  }
  __syncthreads();
  for (int i = t; i < cc; i += 512) {
    unsigned u = ent[i];
    int slot = atomicAdd(&pos[u >> 24], 1);
    csr[s0 + slot] = (int)(u & 0xFFFFFFu);
  }
}

// fold + group-select helpers for the agg accumulators
#define FOLD2(X)                                                              \
  {                                                                           \
    _Pragma("unroll") for (int j = 0; j < 4; ++j) {                           \
      X[j].x += __shfl_xor(X[j].x, 8, 64);  X[j].y += __shfl_xor(X[j].y, 8, 64);   \
      X[j].x += __shfl_xor(X[j].x, 16, 64); X[j].y += __shfl_xor(X[j].y, 16, 64);  \
      X[j].x += __shfl_xor(X[j].x, 32, 64); X[j].y += __shfl_xor(X[j].y, 32, 64);  \
    }                                                                         \
  }
#define GSEL(X, mv, g)                                                        \
  {                                                                           \
    float vv[8] = {X[0].x, X[0].y, X[1].x, X[1].y, X[2].x, X[2].y, X[3].x, X[3].y};\
    mv = vv[0];                                                               \
    _Pragma("unroll") for (int j = 1; j < 8; ++j) if ((g) == j) mv = vv[j];   \
  }

// ---------------------------------------------------------------------------
// AGG x4 on fp8 rows (64B/row, uint2=8B/lane): wave aggregates FOUR nodes;
// peeled first iteration issues 8 independent dwordx2 gathers.
// ---------------------------------------------------------------------------
__device__ inline void agg4(const unsigned char* __restrict__ feat8,
                            const int* __restrict__ rs, const int* __restrict__ re_,
                            const int* __restrict__ csr, int n0, int N,
                            int g, int t,
                            float& m0o, float& m1o, float& m2o, float& m3o) {
  int s0 = rs[n0],     en0 = re_[n0];
  int s1 = rs[n0 + 1], en1 = re_[n0 + 1];
  int s2 = rs[n0 + 2], en2 = re_[n0 + 2];
  int s3 = rs[n0 + 3], en3 = re_[n0 + 3];
  float2 A[4] = {{0.f,0.f},{0.f,0.f},{0.f,0.f},{0.f,0.f}};
  float2 B[4] = {{0.f,0.f},{0.f,0.f},{0.f,0.f},{0.f,0.f}};
  float2 C[4] = {{0.f,0.f},{0.f,0.f},{0.f,0.f},{0.f,0.f}};
  float2 E[4] = {{0.f,0.f},{0.f,0.f},{0.f,0.f},{0.f,0.f}};
  int e0 = s0 + g, e1 = s1 + g, e2 = s2 + g, e3 = s3 + g;
  {   // peel: 8 loads in flight across 4 nodes
    bool v0a = e0 < en0, v0b = e0 + 8 < en0;
    bool v1a = e1 < en1, v1b = e1 + 8 < en1;
    bool v2a = e2 < en2, v2b = e2 + 8 < en2;
    bool v3a = e3 < en3, v3b = e3 + 8 < en3;
    int i0a = min(csr[min(e0,     max(en0 - 1, 0))], N - 1);
    int i0b = min(csr[min(e0 + 8, max(en0 - 1, 0))], N - 1);
    int i1a = min(csr[min(e1,     max(en1 - 1, 0))], N - 1);
    int i1b = min(csr[min(e1 + 8, max(en1 - 1, 0))], N - 1);
    int i2a = min(csr[min(e2,     max(en2 - 1, 0))], N - 1);
    int i2b = min(csr[min(e2 + 8, max(en2 - 1, 0))], N - 1);
    int i3a = min(csr[min(e3,     max(en3 - 1, 0))], N - 1);
    int i3b = min(csr[min(e3 + 8, max(en3 - 1, 0))], N - 1);
    uint2 r0a = *reinterpret_cast<const uint2*>(feat8 + (size_t)i0a * 64 + t * 8);
    uint2 r0b = *reinterpret_cast<const uint2*>(feat8 + (size_t)i0b * 64 + t * 8);
    uint2 r1a = *reinterpret_cast<const uint2*>(feat8 + (size_t)i1a * 64 + t * 8);
    uint2 r1b = *reinterpret_cast<const uint2*>(feat8 + (size_t)i1b * 64 + t * 8);
    uint2 r2a = *reinterpret_cast<const uint2*>(feat8 + (size_t)i2a * 64 + t * 8);
    uint2 r2b = *reinterpret_cast<const uint2*>(feat8 + (size_t)i2b * 64 + t * 8);
    uint2 r3a = *reinterpret_cast<const uint2*>(feat8 + (size_t)i3a * 64 + t * 8);
    uint2 r3b = *reinterpret_cast<const uint2*>(feat8 + (size_t)i3b * 64 + t * 8);
    if (v0a) addrow8(A, r0a);
    if (v0b) addrow8(A, r0b);
    if (v1a) addrow8(B, r1a);
    if (v1b) addrow8(B, r1b);
    if (v2a) addrow8(C, r2a);
    if (v2b) addrow8(C, r2b);
    if (v3a) addrow8(E, r3a);
    if (v3b) addrow8(E, r3b);
    e0 += 16; e1 += 16; e2 += 16; e3 += 16;
  }
  for (; e0 + 8 < en0; e0 += 16) {
    uint2 r0 = *reinterpret_cast<const uint2*>(feat8 + (size_t)csr[e0] * 64 + t * 8);
    uint2 r1 = *reinterpret_cast<const uint2*>(feat8 + (size_t)csr[e0 + 8] * 64 + t * 8);
    addrow8(A, r0); addrow8(A, r1);
  }
  if (e0 < en0) {
    uint2 r0 = *reinterpret_cast<const uint2*>(feat8 + (size_t)csr[e0] * 64 + t * 8);
    addrow8(A, r0);
  }
  for (; e1 + 8 < en1; e1 += 16) {
    uint2 r0 = *reinterpret_cast<const uint2*>(feat8 + (size_t)csr[e1] * 64 + t * 8);
    uint2 r1 = *reinterpret_cast<const uint2*>(feat8 + (size_t)csr[e1 + 8] * 64 + t * 8);
    addrow8(B, r0); addrow8(B, r1);
  }
  if (e1 < en1) {
    uint2 r0 = *reinterpret_cast<const uint2*>(feat8 + (size_t)csr[e1] * 64 + t * 8);
    addrow8(B, r0);
  }
  for (; e2 + 8 < en2; e2 += 16) {
    uint2 r0 = *reinterpret_cast<const uint2*>(feat8 + (size_t)csr[e2] * 64 + t * 8);
    uint2 r1 = *reinterpret_cast<const uint2*>(feat8 + (size_t)csr[e2 + 8] * 64 + t * 8);
    addrow8(C, r0); addrow8(C, r1);
  }
  if (e2 < en2) {
    uint2 r0 = *reinterpret_cast<const uint2*>(feat8 + (size_t)csr[e2] * 64 + t * 8);
    addrow8(C, r0);
  }
  for (; e3 + 8 < en3; e3 += 16) {
    uint2 r0 = *reinterpret_cast<const uint2*>(feat8 + (size_t)csr[e3] * 64 + t * 8);
    uint2 r1 = *reinterpret_cast<const uint2*>(feat8 + (size_t)csr[e3 + 8] * 64 + t * 8);
    addrow8(E, r0); addrow8(E, r1);
  }
  if (e3 < en3) {
    uint2 r0 = *reinterpret_cast<const uint2*>(feat8 + (size_t)csr[e3] * 64 + t * 8);
    addrow8(E, r0);
  }
  FOLD2(A) FOLD2(B) FOLD2(C) FOLD2(E)
  float mv0, mv1, mv2, mv3;
  GSEL(A, mv0, g) GSEL(B, mv1, g) GSEL(C, mv2, g) GSEL(E, mv3, g)
  m0o = mv0 / fmaxf((float)(en0 - s0), 1.0f);
  m1o = mv1 / fmaxf((float)(en1 - s1), 1.0f);
  m2o = mv2 / fmaxf((float)(en2 - s2), 1.0f);
  m3o = mv3 / fmaxf((float)(en3 - s3), 1.0f);
}

// ---------------------------------------------------------------------------
// Fused layer 1: 256 threads = 4 waves, block owns one 16-node tile.
// Phase A: agg4 on xf8 -> msL[16][64] bf16. Phase B: wave 0 MFMA lin; writes
// h as bf16 (self/A-frags) AND fp8 (layer-2 gather).
// ---------------------------------------------------------------------------
__global__ __launch_bounds__(256) void fused1_kernel(
    const unsigned short* __restrict__ xbf, const unsigned char* __restrict__ xf8,
    const int* __restrict__ rs, const int* __restrict__ re_,
    const int* __restrict__ csr, const unsigned short* __restrict__ Wcat,
    const float* __restrict__ b1, unsigned short* __restrict__ hbf,
    unsigned char* __restrict__ hf8, int N) {
  __shared__ unsigned short msL[16][64];
  int w = threadIdx.x >> 6;
  int lane = threadIdx.x & 63;
  int g = lane >> 3;
  int t = lane & 7;
  int base = blockIdx.x * 16;
  float m0, m1, m2, m3;
  agg4(xf8, rs, re_, csr, base + w * 4, N, g, t, m0, m1, m2, m3);
  msL[w * 4][t * 8 + g]     = (unsigned short)f2bf(m0);
  msL[w * 4 + 1][t * 8 + g] = (unsigned short)f2bf(m1);
  msL[w * 4 + 2][t * 8 + g] = (unsigned short)f2bf(m2);
  msL[w * 4 + 3][t * 8 + g] = (unsigned short)f2bf(m3);
  __syncthreads();
  if (threadIdx.x < 64) {
    int col = lane & 15;
    int k0 = (lane >> 4) * 8;
    bf16x8v a0 = *(const bf16x8v*)(&msL[col][k0]);
    bf16x8v a1 = *(const bf16x8v*)(&msL[col][32 + k0]);
    const unsigned short* ax = xbf + (size_t)(base + col) * D;
    bf16x8v a2 = *(const bf16x8v*)(ax + k0);
    bf16x8v a3 = *(const bf16x8v*)(ax + 32 + k0);
    f32x4v acc0 = {0.f, 0.f, 0.f, 0.f}, acc1 = acc0, acc2 = acc0, acc3 = acc0;
#define LIN1_CT(CT, ACC)                                                      \
    {                                                                         \
      const unsigned short* wp = Wcat + ((CT)*16 + col) * 128 + k0;           \
      bf16x8v b0 = *(const bf16x8v*)(wp);                                     \
      bf16x8v b1v = *(const bf16x8v*)(wp + 32);                               \
      bf16x8v b2v = *(const bf16x8v*)(wp + 64);                               \
      bf16x8v b3v = *(const bf16x8v*)(wp + 96);                               \
      ACC = __builtin_amdgcn_mfma_f32_16x16x32_bf16(a0, b0, ACC, 0, 0, 0);    \
      ACC = __builtin_amdgcn_mfma_f32_16x16x32_bf16(a1, b1v, ACC, 0, 0, 0);   \
      ACC = __builtin_amdgcn_mfma_f32_16x16x32_bf16(a2, b2v, ACC, 0, 0, 0);   \
      ACC = __builtin_amdgcn_mfma_f32_16x16x32_bf16(a3, b3v, ACC, 0, 0, 0);   \
    }
    LIN1_CT(0, acc0) LIN1_CT(1, acc1) LIN1_CT(2, acc2) LIN1_CT(3, acc3)
#undef LIN1_CT
    int rbase = (lane >> 4) * 4;
    float bias0 = b1[col], bias1 = b1[16 + col], bias2 = b1[32 + col], bias3 = b1[48 + col];
#pragma unroll
    for (int r = 0; r < 4; ++r) {
      float v0 = fmaxf(acc0[r] + bias0, 0.f);
      float v1 = fmaxf(acc1[r] + bias1, 0.f);
      float v2 = fmaxf(acc2[r] + bias2, 0.f);
      float v3 = fmaxf(acc3[r] + bias3, 0.f);
      size_t rowoff = (size_t)(base + rbase + r) * D;
      hbf[rowoff + col]      = (unsigned short)f2bf(v0);
      hbf[rowoff + 16 + col] = (unsigned short)f2bf(v1);
      hbf[rowoff + 32 + col] = (unsigned short)f2bf(v2);
      hbf[rowoff + 48 + col] = (unsigned short)f2bf(v3);
      size_t rowoff8 = (size_t)(base + rbase + r) * 64;
      hf8[rowoff8 + col]      = f2fp8(v0);
      hf8[rowoff8 + 16 + col] = f2fp8(v1);
      hf8[rowoff8 + 32 + col] = f2fp8(v2);
      hf8[rowoff8 + 48 + col] = f2fp8(v3);
    }
  }
}

// ---------------------------------------------------------------------------
// Fused layer 2: agg4 on hf8 -> LDS; wave 0 MFMA lin (self from hbf) +
// log_softmax.
// ---------------------------------------------------------------------------
__global__ __launch_bounds__(256) void fused2_kernel(
    const unsigned short* __restrict__ hbf, const unsigned char* __restrict__ hf8,
    const int* __restrict__ rs, const int* __restrict__ re_,
    const int* __restrict__ csr, const unsigned short* __restrict__ Wcat,
    const float* __restrict__ b2p, float* __restrict__ out, int N) {
  __shared__ unsigned short msL[16][64];
  int w = threadIdx.x >> 6;
  int lane = threadIdx.x & 63;
  int g = lane >> 3;
  int t = lane & 7;
  int base = blockIdx.x * 16;
  float m0, m1, m2, m3;
  agg4(hf8, rs, re_, csr, base + w * 4, N, g, t, m0, m1, m2, m3);
  msL[w * 4][t * 8 + g]     = (unsigned short)f2bf(m0);
  msL[w * 4 + 1][t * 8 + g] = (unsigned short)f2bf(m1);
  msL[w * 4 + 2][t * 8 + g] = (unsigned short)f2bf(m2);
  msL[w * 4 + 3][t * 8 + g] = (unsigned short)f2bf(m3);
  __syncthreads();
  if (threadIdx.x < 64) {
    int col = lane & 15;
    int k0 = (lane >> 4) * 8;
    bf16x8v a0 = *(const bf16x8v*)(&msL[col][k0]);
    bf16x8v a1 = *(const bf16x8v*)(&msL[col][32 + k0]);
    const unsigned short* ah = hbf + (size_t)(base + col) * D;
    bf16x8v a2 = *(const bf16x8v*)(ah + k0);
    bf16x8v a3 = *(const bf16x8v*)(ah + 32 + k0);
    f32x4v acc0 = {0.f, 0.f, 0.f, 0.f}, acc1 = acc0, acc2 = acc0;
#define LIN2_CT(CT, ACC)                                                      \
    {                                                                         \
      const unsigned short* wp = Wcat + ((CT)*16 + col) * 128 + k0;           \
      bf16x8v b0 = *(const bf16x8v*)(wp);                                     \
      bf16x8v b1v = *(const bf16x8v*)(wp + 32);                               \
      bf16x8v b2v = *(const bf16x8v*)(wp + 64);                               \
      bf16x8v b3v = *(const bf16x8v*)(wp + 96);                               \
      ACC = __builtin_amdgcn_mfma_f32_16x16x32_bf16(a0, b0, ACC, 0, 0, 0);    \
      ACC = __builtin_amdgcn_mfma_f32_16x16x32_bf16(a1, b1v, ACC, 0, 0, 0);   \
      ACC = __builtin_amdgcn_mfma_f32_16x16x32_bf16(a2, b2v, ACC, 0, 0, 0);   \
      ACC = __builtin_amdgcn_mfma_f32_16x16x32_bf16(a3, b3v, ACC, 0, 0, 0);   \
    }
    LIN2_CT(0, acc0) LIN2_CT(1, acc1) LIN2_CT(2, acc2)
#undef LIN2_CT
    int rbase = (lane >> 4) * 4;
    float bias0 = b2p[col], bias1 = b2p[16 + col], bias2 = b2p[32 + col];
    bool v2ok = (col < 8);   // cols 32..39 valid only
#pragma unroll
    for (int r = 0; r < 4; ++r) {
      float v0 = acc0[r] + bias0;
      float v1 = acc1[r] + bias1;
      float v2 = v2ok ? (acc2[r] + bias2) : -INFINITY;
      float mx = fmaxf(fmaxf(v0, v1), v2);
      mx = fmaxf(mx, __shfl_xor(mx, 1, 64));
      mx = fmaxf(mx, __shfl_xor(mx, 2, 64));
      mx = fmaxf(mx, __shfl_xor(mx, 4, 64));
      mx = fmaxf(mx, __shfl_xor(mx, 8, 64));
      float sm = expf(v0 - mx) + expf(v1 - mx) + (v2ok ? expf(v2 - mx) : 0.f);
      sm += __shfl_xor(sm, 1, 64);
      sm += __shfl_xor(sm, 2, 64);
      sm += __shfl_xor(sm, 4, 64);
      sm += __shfl_xor(sm, 8, 64);
      float ls = mx + logf(sm);
      size_t rowoff = (size_t)(base + rbase + r) * DOUT;
      out[rowoff + col] = v0 - ls;
      out[rowoff + 16 + col] = v1 - ls;
      if (v2ok) out[rowoff + 32 + col] = v2 - ls;
    }
  }
}

extern "C" void kernel_launch(void* const* d_in, const int* in_sizes, int n_in,
                              void* d_out, int out_size, void* d_ws, size_t ws_size,
                              hipStream_t stream) {
  const float* x   = (const float*)d_in[0];
  const int*   ei  = (const int*)d_in[1];
  const float* W1l = (const float*)d_in[2];
  const float* b1  = (const float*)d_in[3];
  const float* W1r = (const float*)d_in[4];
  const float* W2l = (const float*)d_in[5];
  const float* b2  = (const float*)d_in[6];
  const float* W2r = (const float*)d_in[7];
  float* out = (float*)d_out;

  const int* src = ei;
  const int* dst = ei + N_EDGES;

  // Workspace (~48.1 MB): xbf | hbf | csr | rs | re | bcnt | binned(->hf8) |
  // Wcat1 | Wcat2 | b2p | xf8.
  char* ws = (char*)d_ws;
  size_t featB = (size_t)N_NODES * D * sizeof(unsigned short);  // 12.8 MB
  unsigned short* xbf = (unsigned short*)ws;
  unsigned short* hbf = (unsigned short*)(ws + featB);
  int* csr  = (int*)(ws + 2 * featB);                           // NBUCK*BCAP ints (~7.6 MB)
  int* rs   = csr + (size_t)NBUCK * BCAP;
  int* re_  = rs + N_NODES;
  int* bcnt = re_ + N_NODES;
  char* scratch = (char*)(bcnt + NBUCK);
  scratch = (char*)(((uintptr_t)scratch + 15) & ~(uintptr_t)15);
  unsigned* binned      = (unsigned*)scratch;                   // NBUCK*BCAP (~7.6 MB)
  unsigned char* hf8    = (unsigned char*)scratch;              // 6.4 MB (after fine)
  unsigned short* Wcat1 = (unsigned short*)(scratch + (size_t)NBUCK * BCAP * 4);
  unsigned short* Wcat2 = Wcat1 + 64 * 128;
  float* b2p            = (float*)(Wcat2 + 48 * 128);
  unsigned char* xf8    = (unsigned char*)(b2p + 48);           // 6.4 MB

  const int NTILES = N_NODES / 16;   // 6250 (N % 16 == 0)

  // ---- fused prep: cvt (bf16 + fp8) + wcvt + single-pass bucket scatter ----
  hipMemsetAsync(bcnt, 0, NBUCK * sizeof(int), stream);
  prep_kernel<<<NCHUNK, PTHREADS, 0, stream>>>(x, xbf, xf8, W1l, W1r, W2l, W2r, b2,
                                               Wcat1, Wcat2, b2p, src, dst, bcnt, binned);
  fine_kernel<<<NBUCK, 512, 0, stream>>>(binned, bcnt, rs, re_, csr, N_NODES);

  // ---- fused layers (fp8 gather -> LDS -> wave-0 MFMA lin) ----
  fused1_kernel<<<NTILES, 256, 0, stream>>>(xbf, xf8, rs, re_, csr, Wcat1, b1,
                                            hbf, hf8, N_NODES);
  fused2_kernel<<<NTILES, 256, 0, stream>>>(hbf, hf8, rs, re_, csr, Wcat2, b2p,
                                            out, N_NODES);
}

// Round 19
// 137.078 us; speedup vs baseline: 1.0347x; 1.0347x over previous
//
#include <hip/hip_runtime.h>
#include <math.h>

#define N_NODES 100000
#define N_EDGES 1600000
#define D 64
#define DOUT 40
#define NBUCK ((N_NODES + 255) / 256)    // 391 buckets of 256 dst-nodes
#define CHUNK 4096                       // edges per prep block (write locality!)
#define NCHUNK ((N_EDGES + CHUNK - 1) / CHUNK)  // 391 chunks
#define PTHREADS 512                     // prep block width (8 waves)
#define BCAP 4864                        // bucket region capacity (mean 4096 + 12 sigma)

typedef __attribute__((ext_vector_type(8))) short bf16x8v;   // 8 bf16 (4 VGPRs)
typedef __attribute__((ext_vector_type(4))) float f32x4v;    // MFMA accumulator

__device__ inline float bf2f(unsigned u) {
  union { unsigned i; float f; } v;
  v.i = u << 16;
  return v.f;
}
__device__ inline unsigned f2bf(float f) {
  union { float f; unsigned i; } v;
  v.f = f;
  unsigned r = v.i + 0x7fffu + ((v.i >> 16) & 1u);   // RNE
  return r >> 16;
}
// packed accumulate: two bf16 from one u32 -> float2 +=
__device__ inline void addpk(float2& a, unsigned u) {
  union { unsigned i; float f; } lo, hi;
  lo.i = u << 16;
  hi.i = u & 0xffff0000u;
  a.x += lo.f;
  a.y += hi.f;
}
__device__ inline void addrow4(float2* A, uint4 r) {
  addpk(A[0], r.x); addpk(A[1], r.y); addpk(A[2], r.z); addpk(A[3], r.w);
}

// ---------------------------------------------------------------------------
// prep_kernel: cvt(x->bf16) + weight prep + single-pass bucket scatter.
// (R13 structure: CHUNK=4096 write locality, 512 threads)
// ---------------------------------------------------------------------------
__global__ __launch_bounds__(PTHREADS) void prep_kernel(
    const float* __restrict__ x, unsigned short* __restrict__ xbf,
    const float* __restrict__ W1l, const float* __restrict__ W1r,
    const float* __restrict__ W2l, const float* __restrict__ W2r,
    const float* __restrict__ b2, unsigned short* __restrict__ Wcat1,
    unsigned short* __restrict__ Wcat2, float* __restrict__ b2p,
    const int* __restrict__ src, const int* __restrict__ dst,
    int* __restrict__ bcnt, unsigned* __restrict__ binned) {
  __shared__ unsigned ent[CHUNK];
  __shared__ unsigned short sbk[CHUNK];
  __shared__ int cnt[512], scn[512], pos[512], base[512];
  int t = threadIdx.x;
  int blk = blockIdx.x;
  int gtid = blk * PTHREADS + t;
  int nth = NCHUNK * PTHREADS;

  const int n8 = N_NODES * D / 8;
  for (int i = gtid; i < n8; i += nth) {
    const float4* p = reinterpret_cast<const float4*>(x) + (size_t)i * 2;
    float4 a = p[0], b = p[1];
    uint4 o;
    o.x = f2bf(a.x) | (f2bf(a.y) << 16);
    o.y = f2bf(a.z) | (f2bf(a.w) << 16);
    o.z = f2bf(b.x) | (f2bf(b.y) << 16);
    o.w = f2bf(b.z) | (f2bf(b.w) << 16);
    reinterpret_cast<uint4*>(xbf)[i] = o;
  }
  const int NW = 64 * 128 + 48 * 128 + 48;
  for (int i = gtid; i < NW; i += nth) {
    if (i < 64 * 128) {
      int o = i >> 7, k = i & 127;
      float v = (k < 64) ? W1l[o * 64 + k] : W1r[o * 64 + (k - 64)];
      Wcat1[i] = (unsigned short)f2bf(v);
    } else if (i < 64 * 128 + 48 * 128) {
      int j = i - 64 * 128;
      int o = j >> 7, k = j & 127;
      float v = (o < DOUT) ? ((k < 64) ? W2l[o * 64 + k] : W2r[o * 64 + (k - 64)]) : 0.0f;
      Wcat2[j] = (unsigned short)f2bf(v);
    } else {
      int j = i - 64 * 128 - 48 * 128;
      b2p[j] = (j < DOUT) ? b2[j] : 0.0f;
    }
  }
  cnt[t] = 0;
  __syncthreads();
  int cbase = blk * CHUNK;
  int cc = min(CHUNK, N_EDGES - cbase);
  unsigned my_e[8];
  int my_b[8];
  int nmine = 0;
#pragma unroll
  for (int i = 0; i < 8; ++i) {
    int li = t + i * PTHREADS;
    if (li < cc) {
      int s = src[cbase + li];
      int d = dst[cbase + li];
      int b = d >> 8;
      my_e[nmine] = ((unsigned)(d & 255) << 24) | (unsigned)s;
      my_b[nmine] = b;
      nmine++;
      atomicAdd(&cnt[b], 1);
    }
  }
  __syncthreads();
  scn[t] = cnt[t];
  __syncthreads();
  for (int off = 1; off < 512; off <<= 1) {
    int v = (t >= off) ? scn[t - off] : 0;
    __syncthreads();
    scn[t] += v;
    __syncthreads();
  }
  pos[t] = scn[t] - cnt[t];
  __syncthreads();
  for (int i = 0; i < nmine; ++i) {
    int slot = atomicAdd(&pos[my_b[i]], 1);
    ent[slot] = my_e[i];
    sbk[slot] = (unsigned short)my_b[i];
  }
  __syncthreads();
  for (int b = t; b < NBUCK; b += PTHREADS)
    if (cnt[b] > 0) base[b] = atomicAdd(&bcnt[b], cnt[b]);
  __syncthreads();
  for (int i = t; i < cc; i += PTHREADS) {
    int b = sbk[i];
    int excl = scn[b] - cnt[b];
    binned[(size_t)b * BCAP + base[b] + (i - excl)] = ent[i];
  }
}

// ---------------------------------------------------------------------------
// fine_kernel: per-bucket counting-sort -> csr (fixed regions) + rs/re.
// ---------------------------------------------------------------------------
__global__ __launch_bounds__(512) void fine_kernel(
    const unsigned* __restrict__ binned, const int* __restrict__ bcnt,
    int* __restrict__ rs, int* __restrict__ re_, int* __restrict__ csr, int N) {
  __shared__ unsigned ent[BCAP];
  __shared__ int c[256], p[256], pos[256];
  int b = blockIdx.x;
  int t = threadIdx.x;
  int cc = bcnt[b];
  int s0 = b * BCAP;
  if (t < 256) c[t] = 0;
  __syncthreads();
  for (int i = t; i < cc; i += 512) {
    unsigned u = binned[s0 + i];
    ent[i] = u;
    atomicAdd(&c[u >> 24], 1);
  }
  __syncthreads();
  if (t < 256) p[t] = c[t];
  __syncthreads();
  for (int off = 1; off < 256; off <<= 1) {
    int v = 0;
    if (t < 256 && t >= off) v = p[t - off];
    __syncthreads();
    if (t < 256) p[t] += v;
    __syncthreads();
  }
  if (t < 256) {
    int excl = p[t] - c[t];
    int node = b * 256 + t;
    if (node < N) {
      rs[node] = s0 + excl;
      re_[node] = s0 + excl + c[t];
    }
    pos[t] = excl;
  }
  __syncthreads();
  for (int i = t; i < cc; i += 512) {
    unsigned u = ent[i];
    int slot = atomicAdd(&pos[u >> 24], 1);
    csr[s0 + slot] = (int)(u & 0xFFFFFFu);
  }
}

// fold + group-select helpers for the agg accumulators
#define FOLD2(X)                                                              \
  {                                                                           \
    _Pragma("unroll") for (int j = 0; j < 4; ++j) {                           \
      X[j].x += __shfl_xor(X[j].x, 8, 64);  X[j].y += __shfl_xor(X[j].y, 8, 64);   \
      X[j].x += __shfl_xor(X[j].x, 16, 64); X[j].y += __shfl_xor(X[j].y, 16, 64);  \
      X[j].x += __shfl_xor(X[j].x, 32, 64); X[j].y += __shfl_xor(X[j].y, 32, 64);  \
    }                                                                         \
  }
#define GSEL(X, mv, g)                                                        \
  {                                                                           \
    float vv[8] = {X[0].x, X[0].y, X[1].x, X[1].y, X[2].x, X[2].y, X[3].x, X[3].y};\
    mv = vv[0];                                                               \
    _Pragma("unroll") for (int j = 1; j < 8; ++j) if ((g) == j) mv = vv[j];   \
  }

// ---------------------------------------------------------------------------
// AGG x4: wave aggregates FOUR nodes; peeled first iteration issues 8
// independent dwordx4 gathers (2/node) before consumption -> 2x the in-flight
// transactions of R14's 2-node version. Remainder loops per node (rare).
// ---------------------------------------------------------------------------
__device__ inline void agg4(const unsigned short* __restrict__ feat,
                            const int* __restrict__ rs, const int* __restrict__ re_,
                            const int* __restrict__ csr, int n0, int N,
                            int g, int t,
                            float& m0o, float& m1o, float& m2o, float& m3o) {
  int s0 = rs[n0],     en0 = re_[n0];
  int s1 = rs[n0 + 1], en1 = re_[n0 + 1];
  int s2 = rs[n0 + 2], en2 = re_[n0 + 2];
  int s3 = rs[n0 + 3], en3 = re_[n0 + 3];
  float2 A[4] = {{0.f,0.f},{0.f,0.f},{0.f,0.f},{0.f,0.f}};
  float2 B[4] = {{0.f,0.f},{0.f,0.f},{0.f,0.f},{0.f,0.f}};
  float2 C[4] = {{0.f,0.f},{0.f,0.f},{0.f,0.f},{0.f,0.f}};
  float2 E[4] = {{0.f,0.f},{0.f,0.f},{0.f,0.f},{0.f,0.f}};
  int e0 = s0 + g, e1 = s1 + g, e2 = s2 + g, e3 = s3 + g;
  {   // peel: 8 loads in flight across 4 nodes
    bool v0a = e0 < en0, v0b = e0 + 8 < en0;
    bool v1a = e1 < en1, v1b = e1 + 8 < en1;
    bool v2a = e2 < en2, v2b = e2 + 8 < en2;
    bool v3a = e3 < en3, v3b = e3 + 8 < en3;
    int i0a = min(csr[min(e0,     max(en0 - 1, 0))], N - 1);
    int i0b = min(csr[min(e0 + 8, max(en0 - 1, 0))], N - 1);
    int i1a = min(csr[min(e1,     max(en1 - 1, 0))], N - 1);
    int i1b = min(csr[min(e1 + 8, max(en1 - 1, 0))], N - 1);
    int i2a = min(csr[min(e2,     max(en2 - 1, 0))], N - 1);
    int i2b = min(csr[min(e2 + 8, max(en2 - 1, 0))], N - 1);
    int i3a = min(csr[min(e3,     max(en3 - 1, 0))], N - 1);
    int i3b = min(csr[min(e3 + 8, max(en3 - 1, 0))], N - 1);
    uint4 r0a = *reinterpret_cast<const uint4*>(feat + (size_t)i0a * D + t * 8);
    uint4 r0b = *reinterpret_cast<const uint4*>(feat + (size_t)i0b * D + t * 8);
    uint4 r1a = *reinterpret_cast<const uint4*>(feat + (size_t)i1a * D + t * 8);
    uint4 r1b = *reinterpret_cast<const uint4*>(feat + (size_t)i1b * D + t * 8);
    uint4 r2a = *reinterpret_cast<const uint4*>(feat + (size_t)i2a * D + t * 8);
    uint4 r2b = *reinterpret_cast<const uint4*>(feat + (size_t)i2b * D + t * 8);
    uint4 r3a = *reinterpret_cast<const uint4*>(feat + (size_t)i3a * D + t * 8);
    uint4 r3b = *reinterpret_cast<const uint4*>(feat + (size_t)i3b * D + t * 8);
    if (v0a) addrow4(A, r0a);
    if (v0b) addrow4(A, r0b);
    if (v1a) addrow4(B, r1a);
    if (v1b) addrow4(B, r1b);
    if (v2a) addrow4(C, r2a);
    if (v2b) addrow4(C, r2b);
    if (v3a) addrow4(E, r3a);
    if (v3b) addrow4(E, r3b);
    e0 += 16; e1 += 16; e2 += 16; e3 += 16;
  }
  // remainders (deg > 16+g): per-node pair loops + tails
  for (; e0 + 8 < en0; e0 += 16) {
    uint4 r0 = *reinterpret_cast<const uint4*>(feat + (size_t)csr[e0] * D + t * 8);
    uint4 r1 = *reinterpret_cast<const uint4*>(feat + (size_t)csr[e0 + 8] * D + t * 8);
    addrow4(A, r0); addrow4(A, r1);
  }
  if (e0 < en0) {
    uint4 r0 = *reinterpret_cast<const uint4*>(feat + (size_t)csr[e0] * D + t * 8);
    addrow4(A, r0);
  }
  for (; e1 + 8 < en1; e1 += 16) {
    uint4 r0 = *reinterpret_cast<const uint4*>(feat + (size_t)csr[e1] * D + t * 8);
    uint4 r1 = *reinterpret_cast<const uint4*>(feat + (size_t)csr[e1 + 8] * D + t * 8);
    addrow4(B, r0); addrow4(B, r1);
  }
  if (e1 < en1) {
    uint4 r0 = *reinterpret_cast<const uint4*>(feat + (size_t)csr[e1] * D + t * 8);
    addrow4(B, r0);
  }
  for (; e2 + 8 < en2; e2 += 16) {
    uint4 r0 = *reinterpret_cast<const uint4*>(feat + (size_t)csr[e2] * D + t * 8);
    uint4 r1 = *reinterpret_cast<const uint4*>(feat + (size_t)csr[e2 + 8] * D + t * 8);
    addrow4(C, r0); addrow4(C, r1);
  }
  if (e2 < en2) {
    uint4 r0 = *reinterpret_cast<const uint4*>(feat + (size_t)csr[e2] * D + t * 8);
    addrow4(C, r0);
  }
  for (; e3 + 8 < en3; e3 += 16) {
    uint4 r0 = *reinterpret_cast<const uint4*>(feat + (size_t)csr[e3] * D + t * 8);
    uint4 r1 = *reinterpret_cast<const uint4*>(feat + (size_t)csr[e3 + 8] * D + t * 8);
    addrow4(E, r0); addrow4(E, r1);
  }
  if (e3 < en3) {
    uint4 r0 = *reinterpret_cast<const uint4*>(feat + (size_t)csr[e3] * D + t * 8);
    addrow4(E, r0);
  }
  FOLD2(A) FOLD2(B) FOLD2(C) FOLD2(E)
  float mv0, mv1, mv2, mv3;
  GSEL(A, mv0, g) GSEL(B, mv1, g) GSEL(C, mv2, g) GSEL(E, mv3, g)
  m0o = mv0 / fmaxf((float)(en0 - s0), 1.0f);
  m1o = mv1 / fmaxf((float)(en1 - s1), 1.0f);
  m2o = mv2 / fmaxf((float)(en2 - s2), 1.0f);
  m3o = mv3 / fmaxf((float)(en3 - s3), 1.0f);
}

// ---------------------------------------------------------------------------
// Fused layer 1: 256 threads = 4 waves, block owns one 16-node tile.
// Phase A: each wave aggregates 4 nodes (8-load peel) -> msL[16][64] bf16.
// Phase B (R15-proven): wave 0 does the MFMA lin.
// C/D: col=lane&15, row=(lane>>4)*4+reg [m89-verified].
// ---------------------------------------------------------------------------
__global__ __launch_bounds__(256) void fused1_kernel(
    const unsigned short* __restrict__ xbf, const int* __restrict__ rs,
    const int* __restrict__ re_, const int* __restrict__ csr,
    const unsigned short* __restrict__ Wcat, const float* __restrict__ b1,
    unsigned short* __restrict__ hbf, int N) {
  __shared__ unsigned short msL[16][64];
  int w = threadIdx.x >> 6;
  int lane = threadIdx.x & 63;
  int g = lane >> 3;
  int t = lane & 7;
  int base = blockIdx.x * 16;
  float m0, m1, m2, m3;
  agg4(xbf, rs, re_, csr, base + w * 4, N, g, t, m0, m1, m2, m3);
  msL[w * 4][t * 8 + g]     = (unsigned short)f2bf(m0);
  msL[w * 4 + 1][t * 8 + g] = (unsigned short)f2bf(m1);
  msL[w * 4 + 2][t * 8 + g] = (unsigned short)f2bf(m2);
  msL[w * 4 + 3][t * 8 + g] = (unsigned short)f2bf(m3);
  __syncthreads();
  if (threadIdx.x < 64) {
    int col = lane & 15;
    int k0 = (lane >> 4) * 8;
    bf16x8v a0 = *(const bf16x8v*)(&msL[col][k0]);
    bf16x8v a1 = *(const bf16x8v*)(&msL[col][32 + k0]);
    const unsigned short* ax = xbf + (size_t)(base + col) * D;
    bf16x8v a2 = *(const bf16x8v*)(ax + k0);
    bf16x8v a3 = *(const bf16x8v*)(ax + 32 + k0);
    f32x4v acc0 = {0.f, 0.f, 0.f, 0.f}, acc1 = acc0, acc2 = acc0, acc3 = acc0;
#define LIN1_CT(CT, ACC)                                                      \
    {                                                                         \
      const unsigned short* wp = Wcat + ((CT)*16 + col) * 128 + k0;           \
      bf16x8v b0 = *(const bf16x8v*)(wp);                                     \
      bf16x8v b1v = *(const bf16x8v*)(wp + 32);                               \
      bf16x8v b2v = *(const bf16x8v*)(wp + 64);                               \
      bf16x8v b3v = *(const bf16x8v*)(wp + 96);                               \
      ACC = __builtin_amdgcn_mfma_f32_16x16x32_bf16(a0, b0, ACC, 0, 0, 0);    \
      ACC = __builtin_amdgcn_mfma_f32_16x16x32_bf16(a1, b1v, ACC, 0, 0, 0);   \
      ACC = __builtin_amdgcn_mfma_f32_16x16x32_bf16(a2, b2v, ACC, 0, 0, 0);   \
      ACC = __builtin_amdgcn_mfma_f32_16x16x32_bf16(a3, b3v, ACC, 0, 0, 0);   \
    }
    LIN1_CT(0, acc0) LIN1_CT(1, acc1) LIN1_CT(2, acc2) LIN1_CT(3, acc3)
#undef LIN1_CT
    int rbase = (lane >> 4) * 4;
    float bias0 = b1[col], bias1 = b1[16 + col], bias2 = b1[32 + col], bias3 = b1[48 + col];
#pragma unroll
    for (int r = 0; r < 4; ++r) {
      size_t rowoff = (size_t)(base + rbase + r) * D;
      hbf[rowoff + col]      = (unsigned short)f2bf(fmaxf(acc0[r] + bias0, 0.f));
      hbf[rowoff + 16 + col] = (unsigned short)f2bf(fmaxf(acc1[r] + bias1, 0.f));
      hbf[rowoff + 32 + col] = (unsigned short)f2bf(fmaxf(acc2[r] + bias2, 0.f));
      hbf[rowoff + 48 + col] = (unsigned short)f2bf(fmaxf(acc3[r] + bias3, 0.f));
    }
  }
}

// ---------------------------------------------------------------------------
// Fused layer 2: agg4(hbf) -> LDS; wave 0 does MFMA lin + log_softmax (R15).
// ---------------------------------------------------------------------------
__global__ __launch_bounds__(256) void fused2_kernel(
    const unsigned short* __restrict__ hbf, const int* __restrict__ rs,
    const int* __restrict__ re_, const int* __restrict__ csr,
    const unsigned short* __restrict__ Wcat, const float* __restrict__ b2p,
    float* __restrict__ out, int N) {
  __shared__ unsigned short msL[16][64];
  int w = threadIdx.x >> 6;
  int lane = threadIdx.x & 63;
  int g = lane >> 3;
  int t = lane & 7;
  int base = blockIdx.x * 16;
  float m0, m1, m2, m3;
  agg4(hbf, rs, re_, csr, base + w * 4, N, g, t, m0, m1, m2, m3);
  msL[w * 4][t * 8 + g]     = (unsigned short)f2bf(m0);
  msL[w * 4 + 1][t * 8 + g] = (unsigned short)f2bf(m1);
  msL[w * 4 + 2][t * 8 + g] = (unsigned short)f2bf(m2);
  msL[w * 4 + 3][t * 8 + g] = (unsigned short)f2bf(m3);
  __syncthreads();
  if (threadIdx.x < 64) {
    int col = lane & 15;
    int k0 = (lane >> 4) * 8;
    bf16x8v a0 = *(const bf16x8v*)(&msL[col][k0]);
    bf16x8v a1 = *(const bf16x8v*)(&msL[col][32 + k0]);
    const unsigned short* ah = hbf + (size_t)(base + col) * D;
    bf16x8v a2 = *(const bf16x8v*)(ah + k0);
    bf16x8v a3 = *(const bf16x8v*)(ah + 32 + k0);
    f32x4v acc0 = {0.f, 0.f, 0.f, 0.f}, acc1 = acc0, acc2 = acc0;
#define LIN2_CT(CT, ACC)                                                      \
    {                                                                         \
      const unsigned short* wp = Wcat + ((CT)*16 + col) * 128 + k0;           \
      bf16x8v b0 = *(const bf16x8v*)(wp);                                     \
      bf16x8v b1v = *(const bf16x8v*)(wp + 32);                               \
      bf16x8v b2v = *(const bf16x8v*)(wp + 64);                               \
      bf16x8v b3v = *(const bf16x8v*)(wp + 96);                               \
      ACC = __builtin_amdgcn_mfma_f32_16x16x32_bf16(a0, b0, ACC, 0, 0, 0);    \
      ACC = __builtin_amdgcn_mfma_f32_16x16x32_bf16(a1, b1v, ACC, 0, 0, 0);   \
      ACC = __builtin_amdgcn_mfma_f32_16x16x32_bf16(a2, b2v, ACC, 0, 0, 0);   \
      ACC = __builtin_amdgcn_mfma_f32_16x16x32_bf16(a3, b3v, ACC, 0, 0, 0);   \
    }
    LIN2_CT(0, acc0) LIN2_CT(1, acc1) LIN2_CT(2, acc2)
#undef LIN2_CT
    int rbase = (lane >> 4) * 4;
    float bias0 = b2p[col], bias1 = b2p[16 + col], bias2 = b2p[32 + col];
    bool v2ok = (col < 8);   // cols 32..39 valid only
#pragma unroll
    for (int r = 0; r < 4; ++r) {
      float v0 = acc0[r] + bias0;
      float v1 = acc1[r] + bias1;
      float v2 = v2ok ? (acc2[r] + bias2) : -INFINITY;
      float mx = fmaxf(fmaxf(v0, v1), v2);
      mx = fmaxf(mx, __shfl_xor(mx, 1, 64));
      mx = fmaxf(mx, __shfl_xor(mx, 2, 64));
      mx = fmaxf(mx, __shfl_xor(mx, 4, 64));
      mx = fmaxf(mx, __shfl_xor(mx, 8, 64));
      float sm = expf(v0 - mx) + expf(v1 - mx) + (v2ok ? expf(v2 - mx) : 0.f);
      sm += __shfl_xor(sm, 1, 64);
      sm += __shfl_xor(sm, 2, 64);
      sm += __shfl_xor(sm, 4, 64);
      sm += __shfl_xor(sm, 8, 64);
      float ls = mx + logf(sm);
      size_t rowoff = (size_t)(base + rbase + r) * DOUT;
      out[rowoff + col] = v0 - ls;
      out[rowoff + 16 + col] = v1 - ls;
      if (v2ok) out[rowoff + 32 + col] = v2 - ls;
    }
  }
}

extern "C" void kernel_launch(void* const* d_in, const int* in_sizes, int n_in,
                              void* d_out, int out_size, void* d_ws, size_t ws_size,
                              hipStream_t stream) {
  const float* x   = (const float*)d_in[0];
  const int*   ei  = (const int*)d_in[1];
  const float* W1l = (const float*)d_in[2];
  const float* b1  = (const float*)d_in[3];
  const float* W1r = (const float*)d_in[4];
  const float* W2l = (const float*)d_in[5];
  const float* b2  = (const float*)d_in[6];
  const float* W2r = (const float*)d_in[7];
  float* out = (float*)d_out;

  const int* src = ei;
  const int* dst = ei + N_EDGES;

  // Workspace: xbf | hbf | csr(fixed regions) | rs | re | bcnt |
  // scratch(binned) | Wcat1 | Wcat2 | b2p.
  char* ws = (char*)d_ws;
  size_t featB = (size_t)N_NODES * D * sizeof(unsigned short);  // 12.8 MB
  unsigned short* xbf = (unsigned short*)ws;
  unsigned short* hbf = (unsigned short*)(ws + featB);
  int* csr  = (int*)(ws + 2 * featB);                           // NBUCK*BCAP ints (~7.3 MB)
  int* rs   = csr + (size_t)NBUCK * BCAP;
  int* re_  = rs + N_NODES;
  int* bcnt = re_ + N_NODES;
  char* scratch = (char*)(bcnt + NBUCK);
  scratch = (char*)(((uintptr_t)scratch + 15) & ~(uintptr_t)15);
  unsigned* binned      = (unsigned*)scratch;                   // NBUCK*BCAP (~7.3 MB)
  unsigned short* Wcat1 = (unsigned short*)(scratch + (size_t)NBUCK * BCAP * 4);
  unsigned short* Wcat2 = Wcat1 + 64 * 128;
  float* b2p            = (float*)(Wcat2 + 48 * 128);

  const int NTILES = N_NODES / 16;   // 6250 (N % 16 == 0)

  // ---- fused prep: cvt + wcvt + single-pass bucket scatter ----
  hipMemsetAsync(bcnt, 0, NBUCK * sizeof(int), stream);
  prep_kernel<<<NCHUNK, PTHREADS, 0, stream>>>(x, xbf, W1l, W1r, W2l, W2r, b2,
                                               Wcat1, Wcat2, b2p, src, dst, bcnt, binned);
  fine_kernel<<<NBUCK, 512, 0, stream>>>(binned, bcnt, rs, re_, csr, N_NODES);

  // ---- fused layers (agg4 -> LDS -> wave-0 MFMA lin) ----
  fused1_kernel<<<NTILES, 256, 0, stream>>>(xbf, rs, re_, csr, Wcat1, b1, hbf, N_NODES);
  fused2_kernel<<<NTILES, 256, 0, stream>>>(hbf, rs, re_, csr, Wcat2, b2p, out, N_NODES);
}